// Round 1
// baseline (3759.834 us; speedup 1.0000x reference)
//
#include <hip/hip_runtime.h>
#include <stdint.h>

#define DEPTH 20
#define FEAT  2048
#define HALF  1024
#define HID   1024
#define MROWS 4096

typedef __bf16 bf16x8 __attribute__((ext_vector_type(8)));
typedef float  f32x4  __attribute__((ext_vector_type(4)));
typedef unsigned int u32x4 __attribute__((ext_vector_type(4)));

__device__ __forceinline__ unsigned short f2bf(float f) {
  union { float f; unsigned int u; } v; v.f = f;
  unsigned int u = v.u + 0x7fffu + ((v.u >> 16) & 1u);
  return (unsigned short)(u >> 16);
}

__device__ __forceinline__ void async_cp16(unsigned short* lds, const unsigned short* g) {
  __builtin_amdgcn_global_load_lds(
      (const __attribute__((address_space(1))) void*)g,
      (__attribute__((address_space(3))) void*)lds, 16, 0, 0);
}

__device__ __forceinline__ bf16x8 lds_ld8(const unsigned short* p) {
  return __builtin_bit_cast(bf16x8, *(const u32x4*)p);
}

// ---------------------------------------------------------------------------
// Weight transpose + cvt: src[k][n] fp32 -> dst[n'][k] bf16.
// For the HID->FEAT matrices (pp=1) output rows are pair-permuted:
//   orig n<1024  (e-half):       p = 64*(n/32) + (n%32)
//   orig n>=1024 (additive half): p = 64*((n-1024)/32) + 32 + ((n-1024)%32)
// so permuted col p (with p%64<32) pairs with p+32, same 64-col wave group.
// ---------------------------------------------------------------------------
__global__ void wcvt_k(const float* __restrict__ s2w1, const float* __restrict__ s2w2,
                       const float* __restrict__ s1w1, const float* __restrict__ s1w2,
                       unsigned short* __restrict__ w2a, unsigned short* __restrict__ w2b,
                       unsigned short* __restrict__ w1a, unsigned short* __restrict__ w1b) {
  const float* src; unsigned short* dst; int N, pp;
  switch (blockIdx.z) {
    case 0:  src = s2w1; dst = w2a; N = 1024; pp = 0; break;
    case 1:  src = s2w2; dst = w2b; N = 2048; pp = 1; break;
    case 2:  src = s1w1; dst = w1a; N = 1024; pp = 0; break;
    default: src = s1w2; dst = w1b; N = 2048; pp = 1; break;
  }
  int nb = blockIdx.x * 32;
  if (nb >= N) return;
  int kb = blockIdx.y * 32;
  __shared__ float t[32][33];
  int tx = threadIdx.x, ty = threadIdx.y;
#pragma unroll
  for (int s = 0; s < 4; ++s)
    t[ty + 8*s][tx] = src[(size_t)(kb + ty + 8*s) * N + nb + tx];
  __syncthreads();
  int pbase = pp ? (nb < 1024 ? 2*nb : 2*(nb - 1024) + 32) : nb;
#pragma unroll
  for (int s = 0; s < 4; ++s) {
    int nl = ty + 8*s;
    dst[(size_t)(pbase + nl) * 1024 + kb + tx] = f2bf(t[tx][nl]);
  }
}

__device__ __forceinline__ int porig(int p) {
  int g = p >> 6, o = p & 63;
  return (o < 32) ? (g*32 + o) : (1024 + g*32 + (o - 32));
}

__global__ void bias_k(const float* __restrict__ s2b1, const float* __restrict__ s2b2,
                       const float* __restrict__ s1b1, const float* __restrict__ s1b2,
                       float* __restrict__ b2a, float* __restrict__ b2b,
                       float* __restrict__ b1a, float* __restrict__ b1b) {
  int i = blockIdx.x * 256 + threadIdx.x;   // 0..6143
  if (i < 1024)      b2a[i] = s2b1[i];
  else if (i < 3072) { int p = i - 1024; b2b[p] = s2b2[porig(p)]; }
  else if (i < 4096) b1a[i - 3072] = s1b1[i - 3072];
  else               { int p = i - 4096; b1b[p] = s1b2[porig(p)]; }
}

// z -> permuted split: x1 fp32, x2 fp32 + bf16
__global__ void permute_k(const float* __restrict__ z, const int* __restrict__ perm,
                          float* __restrict__ x1f, float* __restrict__ x2f,
                          unsigned short* __restrict__ x2b) {
  int c = blockIdx.x * 256 + threadIdx.x;  // grid.x = 8
  int row0 = blockIdx.y * 8;               // grid.y = 512
  int pc = perm[c];
#pragma unroll
  for (int r = 0; r < 8; ++r) {
    int row = row0 + r;
    float v = z[row * FEAT + pc];
    if (c < HALF) {
      x1f[row * HALF + c] = v;
    } else {
      x2f[row * HALF + c - HALF] = v;
      x2b[row * HALF + c - HALF] = f2bf(v);
    }
  }
}

// ---------------------------------------------------------------------------
// GEMM: C[4096 x N] = A[4096 x 1024] * Bt[N x 1024]^T   (bf16 in, fp32 acc)
// 128x128 tile, BK=32, 256 threads (4 waves, 2x2, 64x64 each, 4x4 mfma grid).
// EPI=0: h = lrelu(C + b) -> bf16 hout (N = gridDim.x*128)
// EPI=1: coupling epilogue, N=2048, pair-permuted cols:
//        acc[i][j] (j<2) = e-col, acc[i][j+2] = its additive partner.
// ---------------------------------------------------------------------------
template<int EPI>
__launch_bounds__(256)
__global__ void gemm_k(const unsigned short* __restrict__ A,
                       const unsigned short* __restrict__ Bt,
                       const float* __restrict__ bias,
                       const float* __restrict__ xin,
                       float* __restrict__ yout,
                       unsigned short* __restrict__ ybf,
                       float* __restrict__ jac,
                       unsigned short* __restrict__ hout) {
  __shared__ unsigned short As[128 * 32];
  __shared__ unsigned short Bs[128 * 32];
  const int tid  = threadIdx.x;
  const int wave = tid >> 6, lane = tid & 63;
  const int quad = lane >> 4, l15 = lane & 15;
  const int wy = wave >> 1, wx = wave & 1;
  const int bm = blockIdx.y * 128;
  const int bn = blockIdx.x * 128;
  const int K = 1024;

  f32x4 acc[4][4];
#pragma unroll
  for (int i = 0; i < 4; ++i)
#pragma unroll
    for (int j = 0; j < 4; ++j)
#pragma unroll
      for (int r = 0; r < 4; ++r) acc[i][j][r] = 0.0f;

  const int gbase = wave * 64 + lane;

  for (int kt = 0; kt < 32; ++kt) {
    const int k0 = kt * 32;
#pragma unroll
    for (int i = 0; i < 2; ++i) {
      int g  = i * 256 + gbase;          // granule id, 16B each
      int r  = g >> 2, kg = g & 3;
      async_cp16(&As[(i * 256 + wave * 64) * 8], A  + (size_t)(bm + r) * K + k0 + kg * 8);
      async_cp16(&Bs[(i * 256 + wave * 64) * 8], Bt + (size_t)(bn + r) * K + k0 + kg * 8);
    }
    asm volatile("s_waitcnt vmcnt(0)" ::: "memory");
    __syncthreads();

    bf16x8 af[4], bf[4];
#pragma unroll
    for (int i = 0; i < 4; ++i)
      af[i] = lds_ld8(&As[(wy * 64 + i * 16 + l15) * 32 + quad * 8]);
#pragma unroll
    for (int j = 0; j < 4; ++j)
      bf[j] = lds_ld8(&Bs[(wx * 64 + j * 16 + l15) * 32 + quad * 8]);
#pragma unroll
    for (int i = 0; i < 4; ++i)
#pragma unroll
      for (int j = 0; j < 4; ++j)
        acc[i][j] = __builtin_amdgcn_mfma_f32_16x16x32_bf16(af[i], bf[j], acc[i][j], 0, 0, 0);
    __syncthreads();
  }

  if (EPI == 0) {
    const int ldo = gridDim.x * 128;   // 1024
#pragma unroll
    for (int j = 0; j < 4; ++j) {
      int col = bn + wx * 64 + j * 16 + l15;
      float bj = bias[col];
#pragma unroll
      for (int i = 0; i < 4; ++i) {
#pragma unroll
        for (int r = 0; r < 4; ++r) {
          int row = bm + wy * 64 + i * 16 + quad * 4 + r;
          float v = acc[i][j][r] + bj;
          v = v >= 0.0f ? v : 0.01f * v;
          hout[(size_t)row * ldo + col] = f2bf(v);
        }
      }
    }
  } else {
    const int g = (bn >> 6) + wx;   // 64-col group id in permuted space
#pragma unroll
    for (int i = 0; i < 4; ++i) {
      float esum[4] = {0.0f, 0.0f, 0.0f, 0.0f};
#pragma unroll
      for (int j = 0; j < 2; ++j) {
        int pe = bn + wx * 64 + j * 16 + l15;   // e-col (permuted)
        float be = bias[pe];
        float ba = bias[pe + 32];
        int xcol = g * 32 + j * 16 + l15;        // original col in [0,1024)
#pragma unroll
        for (int r = 0; r < 4; ++r) {
          int row = bm + wy * 64 + i * 16 + quad * 4 + r;
          float re = acc[i][j][r] + be;
          float ra = acc[i][j + 2][r] + ba;
          float e  = 1.2732395447351628f * atanf(0.5f * re);
          float y  = __expf(e) * xin[(size_t)row * HALF + xcol] + ra;
          yout[(size_t)row * FEAT + xcol] = y;
          if (ybf) ybf[(size_t)row * HALF + xcol] = f2bf(y);
          esum[r] += e;
        }
      }
#pragma unroll
      for (int r = 0; r < 4; ++r) {
        float v = esum[r];
        v += __shfl_xor(v, 1);
        v += __shfl_xor(v, 2);
        v += __shfl_xor(v, 4);
        v += __shfl_xor(v, 8);
        if (l15 == 0) {
          int row = bm + wy * 64 + i * 16 + quad * 4 + r;
          atomicAdd(&jac[row], v);
        }
      }
    }
  }
}

__global__ void jcopy_k(const float* __restrict__ jac, float* __restrict__ out) {
  int i = blockIdx.x * 256 + threadIdx.x;
  if (i < 4096) out[i] = jac[i];
}

extern "C" void kernel_launch(void* const* d_in, const int* in_sizes, int n_in,
                              void* d_out, int out_size, void* d_ws, size_t ws_size,
                              hipStream_t stream) {
  const float* x     = (const float*)d_in[0];
  const int*   perms = (const int*)d_in[1];
  const float* s1w1  = (const float*)d_in[2];
  const float* s1b1  = (const float*)d_in[3];
  const float* s1w2  = (const float*)d_in[4];
  const float* s1b2  = (const float*)d_in[5];
  const float* s2w1  = (const float*)d_in[6];
  const float* s2b1  = (const float*)d_in[7];
  const float* s2w2  = (const float*)d_in[8];
  const float* s2b2  = (const float*)d_in[9];
  float* out = (float*)d_out;

  size_t off = 0;
  char* base = (char*)d_ws;
  auto alloc = [&](size_t bytes) {
    void* r = base + off;
    off += (bytes + 255) & ~(size_t)255;
    return r;
  };
  float*          x1f = (float*)alloc((size_t)MROWS * HALF * 4);
  float*          x2f = (float*)alloc((size_t)MROWS * HALF * 4);
  unsigned short* x2b = (unsigned short*)alloc((size_t)MROWS * HALF * 2);
  unsigned short* y1b = (unsigned short*)alloc((size_t)MROWS * HALF * 2);
  unsigned short* hb  = (unsigned short*)alloc((size_t)MROWS * HID * 2);
  float*          zbuf= (float*)alloc((size_t)MROWS * FEAT * 4);
  unsigned short* w2a = (unsigned short*)alloc((size_t)HALF * HID * 2);
  unsigned short* w2b = (unsigned short*)alloc((size_t)FEAT * HID * 2);
  unsigned short* w1a = (unsigned short*)alloc((size_t)HALF * HID * 2);
  unsigned short* w1b = (unsigned short*)alloc((size_t)FEAT * HID * 2);
  float* b2a = (float*)alloc(1024 * 4);
  float* b2b = (float*)alloc(2048 * 4);
  float* b1a = (float*)alloc(1024 * 4);
  float* b1b = (float*)alloc(2048 * 4);
  float* jac = (float*)alloc(4096 * 4);

  hipMemsetAsync(jac, 0, 4096 * 4, stream);

  for (int d = 0; d < DEPTH; ++d) {
    wcvt_k<<<dim3(64, 32, 4), dim3(32, 8), 0, stream>>>(
        s2w1 + (size_t)d * HALF * HID, s2w2 + (size_t)d * HID * FEAT,
        s1w1 + (size_t)d * HALF * HID, s1w2 + (size_t)d * HID * FEAT,
        w2a, w2b, w1a, w1b);
    bias_k<<<24, 256, 0, stream>>>(s2b1 + (size_t)d * HID, s2b2 + (size_t)d * FEAT,
                                   s1b1 + (size_t)d * HID, s1b2 + (size_t)d * FEAT,
                                   b2a, b2b, b1a, b1b);
    const float* zsrc = (d == 0) ? x : zbuf;
    permute_k<<<dim3(8, 512), 256, 0, stream>>>(zsrc, perms + (size_t)d * FEAT, x1f, x2f, x2b);

    float* zdst = (d == DEPTH - 1) ? out : zbuf;
    // subnet 2: r2 = lrelu(x2 @ w2a + b2a) @ w2b + b2b ; y1 = exp(e2)*x1 + r2_add
    gemm_k<0><<<dim3(8, 32), 256, 0, stream>>>(x2b, w2a, b2a, nullptr, nullptr, nullptr, nullptr, hb);
    gemm_k<1><<<dim3(16, 32), 256, 0, stream>>>(hb, w2b, b2b, x1f, zdst, y1b, jac, nullptr);
    // subnet 1: r1 = lrelu(y1 @ w1a + b1a) @ w1b + b1b ; y2 = exp(e1)*x2 + r1_add
    gemm_k<0><<<dim3(8, 32), 256, 0, stream>>>(y1b, w1a, b1a, nullptr, nullptr, nullptr, nullptr, hb);
    gemm_k<1><<<dim3(16, 32), 256, 0, stream>>>(hb, w1b, b1b, x2f, zdst + HALF, nullptr, jac, nullptr);
  }
  jcopy_k<<<16, 256, 0, stream>>>(jac, out + (size_t)MROWS * FEAT);
}